// Round 5
// baseline (600.830 us; speedup 1.0000x reference)
//
#include <hip/hip_runtime.h>

#define AS 20      // alphabet size
#define ASS 400    // AS*AS
#define KK 8
#define BB 256
#define MM 2
#define LL 1024
#define NSWEEP 6

__device__ __forceinline__ float softplus_f(float x) {
    return x > 20.f ? x : log1pf(expf(x));
}

// ---------------- prep + Jacobi eigh per (m,k): 16 blocks x 64 (1 wave) ---
// Outputs: U (m,k,20,20), UT, lam (m,k,20), sp, isp, rho.
__global__ __launch_bounds__(64) void prep_jacobi(
    const float* __restrict__ exch, const float* __restrict__ eqk,
    const float* __restrict__ pmr,
    float* __restrict__ U_g, float* __restrict__ UT_g,
    float* __restrict__ lam_g, float* __restrict__ sp_g,
    float* __restrict__ isp_g, float* __restrict__ rho_g)
{
    const int mk = blockIdx.x;
    const int t = threadIdx.x;
    __shared__ float p[AS], sp[AS], isp[AS], rowsum[AS];
    __shared__ __align__(16) float A[ASS], S[ASS];
    __shared__ float inv_mue_sh;

    const float* Km = exch + (size_t)mk * ASS;
    const float* ev = eqk + (size_t)mk * AS;

    if (t == 0) {
        float mx = -1e30f;
        for (int i = 0; i < AS; i++) mx = fmaxf(mx, ev[i]);
        float sum = 0.f;
        for (int i = 0; i < AS; i++) { float e = expf(ev[i] - mx); p[i] = e; sum += e; }
        for (int i = 0; i < AS; i++) {
            p[i] /= sum;
            sp[i] = sqrtf(p[i]);
            isp[i] = 1.0f / sp[i];
        }
        rho_g[mk] = softplus_f(pmr[mk]);
    }
    __syncthreads();
    // A = R * p_j
    for (int f = t; f < ASS; f += 64) {
        int i = f / AS, j = f % AS;
        float Kv = 0.5f * (Km[i*AS+j] + Km[j*AS+i]);
        float Rv = (i == j) ? 0.f : softplus_f(Kv);
        A[f] = Rv * p[j];
    }
    __syncthreads();
    if (t < AS) {
        float r = 0.f;
        for (int j = 0; j < AS; j++) r += A[t*AS+j];
        rowsum[t] = r;
    }
    __syncthreads();
    if (t == 0) {
        float mue = 0.f;
        for (int i = 0; i < AS; i++) mue += p[i] * rowsum[i];
        inv_mue_sh = 1.0f / fmaxf(mue, 1e-16f);
    }
    __syncthreads();
    // S = sp_i * Q * isp_j (raw)
    for (int f = t; f < ASS; f += 64) {
        int i = f/AS, j = f%AS;
        float Qv = (A[f] - (i==j ? rowsum[i] : 0.f)) * inv_mue_sh;
        S[f] = sp[i] * Qv * isp[j];
    }
    __syncthreads();
    // A = symmetrized Ssym
    for (int f = t; f < ASS; f += 64) {
        int i = f/AS, j = f%AS;
        A[f] = 0.5f * (S[f] + S[j*AS+i]);
    }
    __syncthreads();

    // ---- Jacobi: lane j<20 owns column j of A (col[]) and of V (v[]) ----
    float col[AS], v[AS];
    #pragma unroll
    for (int i = 0; i < AS; ++i) {
        col[i] = (t < AS) ? A[i*AS + t] : 0.f;
        v[i] = (t < AS && i == t) ? 1.f : 0.f;
    }

    for (int sw = 0; sw < NSWEEP; ++sw) {
        #pragma unroll
        for (int r = 0; r < 19; ++r) {
            float cR[10], sR[10];
            float myc = 1.f, mys = 0.f;
            int prt = t, amP = 1;
            // stats + rotation angles from pre-round values (parallel Jacobi)
            #pragma unroll
            for (int idx = 0; idx < 10; ++idx) {
                const int p_ = (idx == 0) ? r : (r + idx) % 19;
                const int q_ = (idx == 0) ? 19 : (r + 19 - idx) % 19;
                const int pp = (p_ < q_) ? p_ : q_;
                const int qq = (p_ < q_) ? q_ : p_;
                float app = __shfl(col[pp], pp);
                float apq = __shfl(col[qq], pp);
                float aqq = __shfl(col[qq], qq);
                float c, s;
                if (fabsf(apq) > 1e-30f) {
                    float th = (aqq - app) / (2.0f * apq);
                    float tt = copysignf(1.0f, th) / (fabsf(th) + sqrtf(1.0f + th*th));
                    c = 1.0f / sqrtf(1.0f + tt*tt);
                    s = tt * c;
                } else { c = 1.f; s = 0.f; }
                cR[idx] = c; sR[idx] = s;
                if (t == pp) { myc = c; mys = s; prt = qq; amP = 1; }
                if (t == qq) { myc = c; mys = s; prt = pp; amP = 0; }
            }
            // row updates (J^T from left): local to each column
            #pragma unroll
            for (int idx = 0; idx < 10; ++idx) {
                const int p_ = (idx == 0) ? r : (r + idx) % 19;
                const int q_ = (idx == 0) ? 19 : (r + 19 - idx) % 19;
                const int pp = (p_ < q_) ? p_ : q_;
                const int qq = (p_ < q_) ? q_ : p_;
                float xp = col[pp], xq = col[qq];
                col[pp] = cR[idx]*xp - sR[idx]*xq;
                col[qq] = sR[idx]*xp + cR[idx]*xq;
            }
            // column updates (J from right): exchange with partner lane
            #pragma unroll
            for (int i = 0; i < AS; ++i) {
                float o  = __shfl(col[i], prt);
                col[i] = amP ? (myc*col[i] - mys*o) : (mys*o + myc*col[i]);
                float vo = __shfl(v[i], prt);
                v[i]   = amP ? (myc*v[i] - mys*vo) : (mys*vo + myc*v[i]);
            }
        }
    }

    // lam = diagonal element of own column (static select chain)
    float lam = 0.f;
    #pragma unroll
    for (int i = 0; i < AS; ++i) lam = (t == i) ? col[i] : lam;

    if (t < AS) {
        lam_g[mk*AS + t] = lam;
        sp_g [mk*AS + t] = sp[t];
        isp_g[mk*AS + t] = isp[t];
        #pragma unroll
        for (int i = 0; i < AS; ++i)
            U_g[(size_t)mk*ASS + i*AS + t] = v[i];   // U[i][t] = V[i,t]
        #pragma unroll
        for (int i4 = 0; i4 < 5; ++i4) {
            float4 w = make_float4(v[4*i4], v[4*i4+1], v[4*i4+2], v[4*i4+3]);
            *(float4*)&UT_g[(size_t)mk*ASS + t*AS + 4*i4] = w;  // UT row t
        }
    }
}

// ---------- build P per (m,b,k): one matmul (U*diag(E))*U^T --------------
__global__ __launch_bounds__(64) void build_P_eig(
    const float* __restrict__ U_g, const float* __restrict__ UT_g,
    const float* __restrict__ lam_g, const float* __restrict__ sp_g,
    const float* __restrict__ isp_g, const float* __restrict__ rho_g,
    const float* __restrict__ tauk, float* __restrict__ Pout)
{
    const int mbk = blockIdx.x;
    const int ki = mbk % KK;
    const int bi = (mbk / KK) % BB;
    const int mi = mbk / (KK * BB);
    const int mk = mi * KK + ki;
    const int t = threadIdx.x;

    __shared__ __align__(16) float Us[ASS], UTs[ASS], Es[AS], sps[AS], isps[AS];

    const float4* Ug4  = (const float4*)(U_g  + (size_t)mk*ASS);
    const float4* UTg4 = (const float4*)(UT_g + (size_t)mk*ASS);
    for (int f = t; f < 100; f += 64) {
        ((float4*)Us)[f]  = Ug4[f];
        ((float4*)UTs)[f] = UTg4[f];
    }
    const float tau = softplus_f(tauk[mi*BB + bi]) * rho_g[mk];
    if (t < AS) {
        Es[t]   = expf(tau * lam_g[mk*AS + t]);
        sps[t]  = sp_g[mk*AS + t];
        isps[t] = isp_g[mk*AS + t];
    }
    __syncthreads();

    if (t < 50) {
        const int i2 = (t / 5) * 2;
        const int c4 = (t % 5) * 4;
        float E[AS];
        #pragma unroll
        for (int q = 0; q < 5; q++) {
            float4 e = ((const float4*)Es)[q];
            E[4*q] = e.x; E[4*q+1] = e.y; E[4*q+2] = e.z; E[4*q+3] = e.w;
        }
        float a0[AS], a1[AS];
        #pragma unroll
        for (int q = 0; q < 5; q++) {
            float4 v0 = *(const float4*)&Us[i2*AS + 4*q];
            float4 v1 = *(const float4*)&Us[(i2+1)*AS + 4*q];
            a0[4*q] = v0.x*E[4*q]; a0[4*q+1] = v0.y*E[4*q+1];
            a0[4*q+2] = v0.z*E[4*q+2]; a0[4*q+3] = v0.w*E[4*q+3];
            a1[4*q] = v1.x*E[4*q]; a1[4*q+1] = v1.y*E[4*q+1];
            a1[4*q+2] = v1.z*E[4*q+2]; a1[4*q+3] = v1.w*E[4*q+3];
        }
        float4 s0 = {0.f,0.f,0.f,0.f}, s1 = {0.f,0.f,0.f,0.f};
        #pragma unroll
        for (int z = 0; z < AS; z++) {
            float4 bv = *(const float4*)&UTs[z*AS + c4];   // row z of U^T
            s0.x = fmaf(a0[z], bv.x, s0.x); s0.y = fmaf(a0[z], bv.y, s0.y);
            s0.z = fmaf(a0[z], bv.z, s0.z); s0.w = fmaf(a0[z], bv.w, s0.w);
            s1.x = fmaf(a1[z], bv.x, s1.x); s1.y = fmaf(a1[z], bv.y, s1.y);
            s1.z = fmaf(a1[z], bv.z, s1.z); s1.w = fmaf(a1[z], bv.w, s1.w);
        }
        float4 spv = *(const float4*)&sps[c4];
        const float i0 = isps[i2], i1 = isps[i2+1];
        float4 o0 = make_float4(i0*s0.x*spv.x, i0*s0.y*spv.y, i0*s0.z*spv.z, i0*s0.w*spv.w);
        float4 o1 = make_float4(i1*s1.x*spv.x, i1*s1.y*spv.y, i1*s1.z*spv.z, i1*s1.w*spv.w);
        float* Po = Pout + (size_t)mbk * ASS;
        *(float4*)&Po[i2*AS + c4] = o0;
        *(float4*)&Po[(i2+1)*AS + c4] = o1;
    }
}

// ---------- apply (round-3, known-good): 1024 blocks x 320 ----------------
__global__ __launch_bounds__(320, 4) void apply_P(
    const float* __restrict__ seq, const float* __restrict__ Pws,
    float* __restrict__ out)
{
    const int blk = blockIdx.x;
    const int mb = blk >> 1;
    const int half = blk & 1;
    const int t = threadIdx.x;
    const int j = t % 40;        // cols 4j..4j+3
    const int rg = t / 40;       // row group 0..7
    const int ki = j / 5;
    const int s0 = (j % 5) * 4;

    float4 Preg[AS];
    const float* Pm = Pws + (size_t)(mb * KK + ki) * ASS + s0;
    #pragma unroll
    for (int z = 0; z < AS; z++) Preg[z] = *(const float4*)(Pm + z * AS);

    __shared__ float4 sbuf[2][320];
    const int rowbase = half * (LL / 2);
    const float* seqb = seq + (size_t)mb * LL * AS;
    float* outb = out + (size_t)mb * LL * (KK * AS);

    {
        const float4* g = (const float4*)(seqb + (size_t)rowbase * AS);
        sbuf[0][t] = g[t];
    }
    __syncthreads();

    for (int c = 0; c < 8; c++) {
        const int cur = c & 1;
        float4 rnext;
        if (c < 7) {
            const float4* g = (const float4*)(seqb + (size_t)(rowbase + (c + 1) * 64) * AS);
            rnext = g[t];
        }
        const int l0 = rowbase + c * 64;
        #pragma unroll
        for (int rr = 0; rr < 8; rr++) {
            const int lr = rg * 8 + rr;
            const float4* row = &sbuf[cur][lr * 5];
            float4 acc = {0.f, 0.f, 0.f, 0.f};
            #pragma unroll
            for (int q = 0; q < 5; q++) {
                float4 sv = row[q];
                acc.x = fmaf(sv.x, Preg[4*q+0].x, acc.x); acc.y = fmaf(sv.x, Preg[4*q+0].y, acc.y);
                acc.z = fmaf(sv.x, Preg[4*q+0].z, acc.z); acc.w = fmaf(sv.x, Preg[4*q+0].w, acc.w);
                acc.x = fmaf(sv.y, Preg[4*q+1].x, acc.x); acc.y = fmaf(sv.y, Preg[4*q+1].y, acc.y);
                acc.z = fmaf(sv.y, Preg[4*q+1].z, acc.z); acc.w = fmaf(sv.y, Preg[4*q+1].w, acc.w);
                acc.x = fmaf(sv.z, Preg[4*q+2].x, acc.x); acc.y = fmaf(sv.z, Preg[4*q+2].y, acc.y);
                acc.z = fmaf(sv.z, Preg[4*q+2].z, acc.z); acc.w = fmaf(sv.z, Preg[4*q+2].w, acc.w);
                acc.x = fmaf(sv.w, Preg[4*q+3].x, acc.x); acc.y = fmaf(sv.w, Preg[4*q+3].y, acc.y);
                acc.z = fmaf(sv.w, Preg[4*q+3].z, acc.z); acc.w = fmaf(sv.w, Preg[4*q+3].w, acc.w);
            }
            *(float4*)&outb[(size_t)(l0 + lr) * 160 + 4 * j] = acc;
        }
        if (c < 7) sbuf[cur ^ 1][t] = rnext;
        __syncthreads();
    }
}

extern "C" void kernel_launch(void* const* d_in, const int* in_sizes, int n_in,
                              void* d_out, int out_size, void* d_ws, size_t ws_size,
                              hipStream_t stream) {
    const float* seq  = (const float*)d_in[0];
    const float* exch = (const float*)d_in[1];
    const float* eqk  = (const float*)d_in[2];
    const float* tauk = (const float*)d_in[3];
    const float* pmr  = (const float*)d_in[4];
    float* out = (float*)d_out;

    float* ws   = (float*)d_ws;
    float* Pws  = ws;                         // 4096*400 = 6.55 MB
    float* Ug   = ws + (size_t)MM*BB*KK*ASS;  // 16*400
    float* UTg  = Ug  + MM*KK*ASS;            // 16*400
    float* lamg = UTg + MM*KK*ASS;            // 16*20
    float* spg  = lamg + MM*KK*AS;            // 16*20
    float* ispg = spg  + MM*KK*AS;            // 16*20
    float* rhog = ispg + MM*KK*AS;            // 16

    prep_jacobi<<<dim3(MM * KK), dim3(64), 0, stream>>>(
        exch, eqk, pmr, Ug, UTg, lamg, spg, ispg, rhog);
    build_P_eig<<<dim3(MM * BB * KK), dim3(64), 0, stream>>>(
        Ug, UTg, lamg, spg, ispg, rhog, tauk, Pws);
    apply_P<<<dim3(MM * BB * 2), dim3(320), 0, stream>>>(seq, Pws, out);
}

// Round 6
// 186.849 us; speedup vs baseline: 3.2156x; 3.2156x over previous
//
#include <hip/hip_runtime.h>

#define AS 20      // alphabet size
#define ASS 400    // AS*AS
#define KK 8
#define BB 256
#define MM 2
#define LL 1024

__device__ __forceinline__ float softplus_f(float x) {
    return x > 20.f ? x : log1pf(expf(x));
}

// ---- 20x20 matmul C = A*B in LDS, 2x4 register-tiled, threads 0..49 ----
__device__ __forceinline__ void mul20(const float* __restrict__ A,
                                      const float* __restrict__ B,
                                      float* __restrict__ C, int t) {
    if (t < 50) {
        const int i2 = (t / 5) * 2;
        const int c4 = (t % 5) * 4;
        float a0[AS], a1[AS];
        #pragma unroll
        for (int q = 0; q < 5; q++) {
            float4 v0 = *(const float4*)&A[i2 * AS + 4 * q];
            float4 v1 = *(const float4*)&A[(i2 + 1) * AS + 4 * q];
            a0[4*q] = v0.x; a0[4*q+1] = v0.y; a0[4*q+2] = v0.z; a0[4*q+3] = v0.w;
            a1[4*q] = v1.x; a1[4*q+1] = v1.y; a1[4*q+2] = v1.z; a1[4*q+3] = v1.w;
        }
        float4 s0 = {0.f,0.f,0.f,0.f}, s1 = {0.f,0.f,0.f,0.f};
        #pragma unroll
        for (int z = 0; z < AS; z++) {
            float4 bv = *(const float4*)&B[z * AS + c4];
            s0.x = fmaf(a0[z], bv.x, s0.x); s0.y = fmaf(a0[z], bv.y, s0.y);
            s0.z = fmaf(a0[z], bv.z, s0.z); s0.w = fmaf(a0[z], bv.w, s0.w);
            s1.x = fmaf(a1[z], bv.x, s1.x); s1.y = fmaf(a1[z], bv.y, s1.y);
            s1.z = fmaf(a1[z], bv.z, s1.z); s1.w = fmaf(a1[z], bv.w, s1.w);
        }
        *(float4*)&C[i2 * AS + c4] = s0;
        *(float4*)&C[(i2 + 1) * AS + c4] = s1;
    }
    __syncthreads();
}

// ---------- prep: per (m,k) build Ssym, sp, isp, rho, infnorm ----------
__global__ __launch_bounds__(64) void prep_S(
    const float* __restrict__ exch, const float* __restrict__ eqk,
    const float* __restrict__ pmr,
    float* __restrict__ Ssym_g, float* __restrict__ sp_g,
    float* __restrict__ isp_g, float* __restrict__ rho_g,
    float* __restrict__ nrm_g)
{
    const int mk = blockIdx.x;
    const int t = threadIdx.x;
    __shared__ float p[AS], sp[AS], isp[AS], rowsum[AS];
    __shared__ float A[ASS], S[ASS];
    __shared__ float inv_mue_sh;

    const float* Km = exch + (size_t)mk * ASS;
    const float* ev = eqk + (size_t)mk * AS;

    if (t == 0) {
        float mx = -1e30f;
        for (int i = 0; i < AS; i++) mx = fmaxf(mx, ev[i]);
        float sum = 0.f;
        for (int i = 0; i < AS; i++) { float e = expf(ev[i] - mx); p[i] = e; sum += e; }
        for (int i = 0; i < AS; i++) {
            p[i] /= sum;
            sp[i] = sqrtf(p[i]);
            isp[i] = 1.0f / sp[i];
        }
        rho_g[mk] = softplus_f(pmr[mk]);
    }
    __syncthreads();
    for (int f = t; f < ASS; f += 64) {
        int i = f / AS, j = f % AS;
        float Kv = 0.5f * (Km[i * AS + j] + Km[j * AS + i]);
        float Rv = (i == j) ? 0.f : softplus_f(Kv);
        A[f] = Rv * p[j];
    }
    __syncthreads();
    if (t < AS) {
        float r = 0.f;
        for (int j = 0; j < AS; j++) r += A[t * AS + j];
        rowsum[t] = r;
    }
    __syncthreads();
    if (t == 0) {
        float mue = 0.f;
        for (int i = 0; i < AS; i++) mue += p[i] * rowsum[i];
        inv_mue_sh = 1.0f / fmaxf(mue, 1e-16f);
    }
    __syncthreads();
    for (int f = t; f < ASS; f += 64) {
        int i = f / AS, j = f % AS;
        float Qv = (A[f] - (i == j ? rowsum[i] : 0.f)) * inv_mue_sh;
        S[f] = sp[i] * Qv * isp[j];
    }
    __syncthreads();
    for (int f = t; f < ASS; f += 64) {
        int i = f / AS, j = f % AS;
        float v = 0.5f * (S[f] + S[j * AS + i]);
        A[f] = v;
        Ssym_g[(size_t)mk * ASS + f] = v;
    }
    __syncthreads();
    if (t < AS) {
        float r = 0.f;
        for (int j = 0; j < AS; j++) r += fabsf(A[t * AS + j]);
        rowsum[t] = r;
    }
    __syncthreads();
    if (t == 0) {
        float n = 0.f;
        for (int i = 0; i < AS; i++) n = fmaxf(n, rowsum[i]);
        nrm_g[mk] = n;
    }
    if (t < AS) { sp_g[mk * AS + t] = sp[t]; isp_g[mk * AS + t] = isp[t]; }
}

// ---------- expm per (m,b,k): Paterson-Stockmeyer deg-9 + squaring ----------
__global__ __launch_bounds__(64) void expm_P(
    const float* __restrict__ Ssym_g, const float* __restrict__ sp_g,
    const float* __restrict__ isp_g, const float* __restrict__ rho_g,
    const float* __restrict__ nrm_g, const float* __restrict__ tauk,
    float* __restrict__ Pout)
{
    const int mbk = blockIdx.x;
    const int ki = mbk % KK;
    const int bi = (mbk / KK) % BB;
    const int mi = mbk / (KK * BB);
    const int mk = mi * KK + ki;
    const int t = threadIdx.x;

    __shared__ float T[ASS], T2[ASS], T3[ASS], Xa[ASS], Xb[ASS];

    const float tau = softplus_f(tauk[mi * BB + bi]) * rho_g[mk];
    const float nt = tau * nrm_g[mk];
    int s = 0;
    if (nt > 1.0f) {
        s = (int)ceilf(log2f(nt));
        if (s < 0) s = 0;
        if (s > 30) s = 30;
    }
    const float sc = ldexpf(tau, -s);

    for (int f = t; f < ASS; f += 64) T[f] = sc * Ssym_g[(size_t)mk * ASS + f];
    __syncthreads();
    mul20(T, T, T2, t);
    mul20(T2, T, T3, t);

    const float C2 = 0.5f, C3 = 1.f/6.f, C4 = 1.f/24.f, C5 = 1.f/120.f,
                C6 = 1.f/720.f, C7 = 1.f/5040.f, C8 = 1.f/40320.f, C9 = 1.f/362880.f;

    // Xa = c6 I + c7 T + c8 T2 + c9 T3
    for (int f = t; f < ASS; f += 64) {
        int i = f / AS, j = f % AS;
        Xa[f] = ((i == j) ? C6 : 0.f) + C7 * T[f] + C8 * T2[f] + C9 * T3[f];
    }
    __syncthreads();
    mul20(T3, Xa, Xb, t);
    // Xa = B1 + Xb
    for (int f = t; f < ASS; f += 64) {
        int i = f / AS, j = f % AS;
        Xa[f] = ((i == j) ? C3 : 0.f) + C4 * T[f] + C5 * T2[f] + Xb[f];
    }
    __syncthreads();
    mul20(T3, Xa, Xb, t);
    // Xa = I + T + 0.5 T2 + Xb
    for (int f = t; f < ASS; f += 64) {
        int i = f / AS, j = f % AS;
        Xa[f] = ((i == j) ? 1.f : 0.f) + T[f] + C2 * T2[f] + Xb[f];
    }
    __syncthreads();
    for (int q = 0; q < s; q++) {
        if ((q & 1) == 0) mul20(Xa, Xa, Xb, t);
        else              mul20(Xb, Xb, Xa, t);
    }

    float* Po = Pout + (size_t)mbk * ASS;
    const float* E = (s & 1) ? Xb : Xa;
    for (int f = t; f < ASS; f += 64) {
        int i = f / AS, j = f % AS;
        Po[f] = isp_g[mk * AS + i] * E[f] * sp_g[mk * AS + j];
    }
}

// ---------- apply (LDS-free): out[mb,l,c] = sum_z seq[mb,l,z]*P[mb,c/20,z,c%20]
// 1024 blocks (mb, half), 320 threads. j=t%40 owns 4 contiguous cols (P col-strip
// in 80 VGPRs); rg=t/40 picks rows. Row data read straight from global: the 40
// lanes of a row-group issue SAME-ADDRESS dwordx4 loads -> 1 coalesced L1 hit.
// Software pipeline: prefetch next row (n*) while computing current (c*).
__global__ __launch_bounds__(320, 3) void apply_P(
    const float* __restrict__ seq, const float* __restrict__ Pws,
    float* __restrict__ out)
{
    const int blk = blockIdx.x;
    const int mb = blk >> 1;
    const int half = blk & 1;
    const int t = threadIdx.x;
    const int j = t % 40;        // cols 4j..4j+3
    const int rg = t / 40;       // row group 0..7
    const int ki = j / 5;
    const int s0 = (j % 5) * 4;

    float4 Preg[AS];
    const float* Pm = Pws + (size_t)(mb * KK + ki) * ASS + s0;
    #pragma unroll
    for (int z = 0; z < AS; z++) Preg[z] = *(const float4*)(Pm + z * AS);

    const int rowbase = half * (LL / 2) + rg * 8;
    const float* seqb = seq + (size_t)mb * LL * AS;
    float* outb = out + (size_t)mb * LL * (KK * AS);

    // iteration it in [0,64): row = rowbase + (it>>3)*64 + (it&7)
    int row = rowbase;
    float4 c0, c1, c2, c3, c4;
    {
        const float4* rp = (const float4*)(seqb + (size_t)row * AS);
        c0 = rp[0]; c1 = rp[1]; c2 = rp[2]; c3 = rp[3]; c4 = rp[4];
    }
    #pragma unroll 2
    for (int it = 0; it < 64; ++it) {
        const int nrow = rowbase + (((it + 1) >> 3) << 6) + ((it + 1) & 7);
        float4 n0, n1, n2, n3, n4;
        if (it < 63) {
            const float4* rp = (const float4*)(seqb + (size_t)nrow * AS);
            n0 = rp[0]; n1 = rp[1]; n2 = rp[2]; n3 = rp[3]; n4 = rp[4];
        }
        float4 acc = {0.f, 0.f, 0.f, 0.f};
        {
            float4 sv;
            sv = c0;
            acc.x = fmaf(sv.x, Preg[0].x, acc.x); acc.y = fmaf(sv.x, Preg[0].y, acc.y);
            acc.z = fmaf(sv.x, Preg[0].z, acc.z); acc.w = fmaf(sv.x, Preg[0].w, acc.w);
            acc.x = fmaf(sv.y, Preg[1].x, acc.x); acc.y = fmaf(sv.y, Preg[1].y, acc.y);
            acc.z = fmaf(sv.y, Preg[1].z, acc.z); acc.w = fmaf(sv.y, Preg[1].w, acc.w);
            acc.x = fmaf(sv.z, Preg[2].x, acc.x); acc.y = fmaf(sv.z, Preg[2].y, acc.y);
            acc.z = fmaf(sv.z, Preg[2].z, acc.z); acc.w = fmaf(sv.z, Preg[2].w, acc.w);
            acc.x = fmaf(sv.w, Preg[3].x, acc.x); acc.y = fmaf(sv.w, Preg[3].y, acc.y);
            acc.z = fmaf(sv.w, Preg[3].z, acc.z); acc.w = fmaf(sv.w, Preg[3].w, acc.w);
            sv = c1;
            acc.x = fmaf(sv.x, Preg[4].x, acc.x); acc.y = fmaf(sv.x, Preg[4].y, acc.y);
            acc.z = fmaf(sv.x, Preg[4].z, acc.z); acc.w = fmaf(sv.x, Preg[4].w, acc.w);
            acc.x = fmaf(sv.y, Preg[5].x, acc.x); acc.y = fmaf(sv.y, Preg[5].y, acc.y);
            acc.z = fmaf(sv.y, Preg[5].z, acc.z); acc.w = fmaf(sv.y, Preg[5].w, acc.w);
            acc.x = fmaf(sv.z, Preg[6].x, acc.x); acc.y = fmaf(sv.z, Preg[6].y, acc.y);
            acc.z = fmaf(sv.z, Preg[6].z, acc.z); acc.w = fmaf(sv.z, Preg[6].w, acc.w);
            acc.x = fmaf(sv.w, Preg[7].x, acc.x); acc.y = fmaf(sv.w, Preg[7].y, acc.y);
            acc.z = fmaf(sv.w, Preg[7].z, acc.z); acc.w = fmaf(sv.w, Preg[7].w, acc.w);
            sv = c2;
            acc.x = fmaf(sv.x, Preg[8].x, acc.x); acc.y = fmaf(sv.x, Preg[8].y, acc.y);
            acc.z = fmaf(sv.x, Preg[8].z, acc.z); acc.w = fmaf(sv.x, Preg[8].w, acc.w);
            acc.x = fmaf(sv.y, Preg[9].x, acc.x); acc.y = fmaf(sv.y, Preg[9].y, acc.y);
            acc.z = fmaf(sv.y, Preg[9].z, acc.z); acc.w = fmaf(sv.y, Preg[9].w, acc.w);
            acc.x = fmaf(sv.z, Preg[10].x, acc.x); acc.y = fmaf(sv.z, Preg[10].y, acc.y);
            acc.z = fmaf(sv.z, Preg[10].z, acc.z); acc.w = fmaf(sv.z, Preg[10].w, acc.w);
            acc.x = fmaf(sv.w, Preg[11].x, acc.x); acc.y = fmaf(sv.w, Preg[11].y, acc.y);
            acc.z = fmaf(sv.w, Preg[11].z, acc.z); acc.w = fmaf(sv.w, Preg[11].w, acc.w);
            sv = c3;
            acc.x = fmaf(sv.x, Preg[12].x, acc.x); acc.y = fmaf(sv.x, Preg[12].y, acc.y);
            acc.z = fmaf(sv.x, Preg[12].z, acc.z); acc.w = fmaf(sv.x, Preg[12].w, acc.w);
            acc.x = fmaf(sv.y, Preg[13].x, acc.x); acc.y = fmaf(sv.y, Preg[13].y, acc.y);
            acc.z = fmaf(sv.y, Preg[13].z, acc.z); acc.w = fmaf(sv.y, Preg[13].w, acc.w);
            acc.x = fmaf(sv.z, Preg[14].x, acc.x); acc.y = fmaf(sv.z, Preg[14].y, acc.y);
            acc.z = fmaf(sv.z, Preg[14].z, acc.z); acc.w = fmaf(sv.z, Preg[14].w, acc.w);
            acc.x = fmaf(sv.w, Preg[15].x, acc.x); acc.y = fmaf(sv.w, Preg[15].y, acc.y);
            acc.z = fmaf(sv.w, Preg[15].z, acc.z); acc.w = fmaf(sv.w, Preg[15].w, acc.w);
            sv = c4;
            acc.x = fmaf(sv.x, Preg[16].x, acc.x); acc.y = fmaf(sv.x, Preg[16].y, acc.y);
            acc.z = fmaf(sv.x, Preg[16].z, acc.z); acc.w = fmaf(sv.x, Preg[16].w, acc.w);
            acc.x = fmaf(sv.y, Preg[17].x, acc.x); acc.y = fmaf(sv.y, Preg[17].y, acc.y);
            acc.z = fmaf(sv.y, Preg[17].z, acc.z); acc.w = fmaf(sv.y, Preg[17].w, acc.w);
            acc.x = fmaf(sv.z, Preg[18].x, acc.x); acc.y = fmaf(sv.z, Preg[18].y, acc.y);
            acc.z = fmaf(sv.z, Preg[18].z, acc.z); acc.w = fmaf(sv.z, Preg[18].w, acc.w);
            acc.x = fmaf(sv.w, Preg[19].x, acc.x); acc.y = fmaf(sv.w, Preg[19].y, acc.y);
            acc.z = fmaf(sv.w, Preg[19].z, acc.z); acc.w = fmaf(sv.w, Preg[19].w, acc.w);
        }
        *(float4*)&outb[(size_t)row * 160 + 4 * j] = acc;
        row = nrow;
        c0 = n0; c1 = n1; c2 = n2; c3 = n3; c4 = n4;
    }
}

extern "C" void kernel_launch(void* const* d_in, const int* in_sizes, int n_in,
                              void* d_out, int out_size, void* d_ws, size_t ws_size,
                              hipStream_t stream) {
    const float* seq  = (const float*)d_in[0];
    const float* exch = (const float*)d_in[1];
    const float* eqk  = (const float*)d_in[2];
    const float* tauk = (const float*)d_in[3];
    const float* pmr  = (const float*)d_in[4];
    float* out = (float*)d_out;

    float* ws   = (float*)d_ws;
    float* Pws  = ws;                        // 4096*400 floats = 6.55 MB
    float* Ssym = ws + (size_t)MM*BB*KK*ASS; // 16*400
    float* spg  = Ssym + MM*KK*ASS;          // 16*20
    float* ispg = spg + MM*KK*AS;            // 16*20
    float* rhog = ispg + MM*KK*AS;           // 16
    float* nrmg = rhog + MM*KK;              // 16

    prep_S<<<dim3(MM * KK), dim3(64), 0, stream>>>(exch, eqk, pmr, Ssym, spg, ispg, rhog, nrmg);
    expm_P<<<dim3(MM * BB * KK), dim3(64), 0, stream>>>(Ssym, spg, ispg, rhog, nrmg, tauk, Pws);
    apply_P<<<dim3(MM * BB * 2), dim3(320), 0, stream>>>(seq, Pws, out);
}

// Round 8
// 114.471 us; speedup vs baseline: 5.2487x; 1.6323x over previous
//
#include <hip/hip_runtime.h>

#define AS 20      // alphabet size
#define ASS 400    // AS*AS
#define KK 8
#define BB 256
#define MM 2
#define LL 1024

typedef float nfloat4 __attribute__((ext_vector_type(4)));

__device__ __forceinline__ float softplus_f(float x) {
    return x > 20.f ? x : log1pf(expf(x));
}

// ---- 20x20 matmul C = A*B in LDS, 2x4 register-tiled, threads 0..49 ----
__device__ __forceinline__ void mul20(const float* __restrict__ A,
                                      const float* __restrict__ B,
                                      float* __restrict__ C, int t) {
    if (t < 50) {
        const int i2 = (t / 5) * 2;
        const int c4 = (t % 5) * 4;
        float a0[AS], a1[AS];
        #pragma unroll
        for (int q = 0; q < 5; q++) {
            float4 v0 = *(const float4*)&A[i2 * AS + 4 * q];
            float4 v1 = *(const float4*)&A[(i2 + 1) * AS + 4 * q];
            a0[4*q] = v0.x; a0[4*q+1] = v0.y; a0[4*q+2] = v0.z; a0[4*q+3] = v0.w;
            a1[4*q] = v1.x; a1[4*q+1] = v1.y; a1[4*q+2] = v1.z; a1[4*q+3] = v1.w;
        }
        float4 s0 = {0.f,0.f,0.f,0.f}, s1 = {0.f,0.f,0.f,0.f};
        #pragma unroll
        for (int z = 0; z < AS; z++) {
            float4 bv = *(const float4*)&B[z * AS + c4];
            s0.x = fmaf(a0[z], bv.x, s0.x); s0.y = fmaf(a0[z], bv.y, s0.y);
            s0.z = fmaf(a0[z], bv.z, s0.z); s0.w = fmaf(a0[z], bv.w, s0.w);
            s1.x = fmaf(a1[z], bv.x, s1.x); s1.y = fmaf(a1[z], bv.y, s1.y);
            s1.z = fmaf(a1[z], bv.z, s1.z); s1.w = fmaf(a1[z], bv.w, s1.w);
        }
        *(float4*)&C[i2 * AS + c4] = s0;
        *(float4*)&C[(i2 + 1) * AS + c4] = s1;
    }
    __syncthreads();
}

// ---------- prep: per (m,k) build Ssym, sp, isp, rho, infnorm ----------
__global__ __launch_bounds__(64) void prep_S(
    const float* __restrict__ exch, const float* __restrict__ eqk,
    const float* __restrict__ pmr,
    float* __restrict__ Ssym_g, float* __restrict__ sp_g,
    float* __restrict__ isp_g, float* __restrict__ rho_g,
    float* __restrict__ nrm_g)
{
    const int mk = blockIdx.x;
    const int t = threadIdx.x;
    __shared__ float p[AS], sp[AS], isp[AS], rowsum[AS];
    __shared__ float A[ASS], S[ASS];
    __shared__ float inv_mue_sh;

    const float* Km = exch + (size_t)mk * ASS;
    const float* ev = eqk + (size_t)mk * AS;

    if (t == 0) {
        float mx = -1e30f;
        for (int i = 0; i < AS; i++) mx = fmaxf(mx, ev[i]);
        float sum = 0.f;
        for (int i = 0; i < AS; i++) { float e = expf(ev[i] - mx); p[i] = e; sum += e; }
        for (int i = 0; i < AS; i++) {
            p[i] /= sum;
            sp[i] = sqrtf(p[i]);
            isp[i] = 1.0f / sp[i];
        }
        rho_g[mk] = softplus_f(pmr[mk]);
    }
    __syncthreads();
    for (int f = t; f < ASS; f += 64) {
        int i = f / AS, j = f % AS;
        float Kv = 0.5f * (Km[i * AS + j] + Km[j * AS + i]);
        float Rv = (i == j) ? 0.f : softplus_f(Kv);
        A[f] = Rv * p[j];
    }
    __syncthreads();
    if (t < AS) {
        float r = 0.f;
        for (int j = 0; j < AS; j++) r += A[t * AS + j];
        rowsum[t] = r;
    }
    __syncthreads();
    if (t == 0) {
        float mue = 0.f;
        for (int i = 0; i < AS; i++) mue += p[i] * rowsum[i];
        inv_mue_sh = 1.0f / fmaxf(mue, 1e-16f);
    }
    __syncthreads();
    for (int f = t; f < ASS; f += 64) {
        int i = f / AS, j = f % AS;
        float Qv = (A[f] - (i == j ? rowsum[i] : 0.f)) * inv_mue_sh;
        S[f] = sp[i] * Qv * isp[j];
    }
    __syncthreads();
    for (int f = t; f < ASS; f += 64) {
        int i = f / AS, j = f % AS;
        float v = 0.5f * (S[f] + S[j * AS + i]);
        A[f] = v;
        Ssym_g[(size_t)mk * ASS + f] = v;
    }
    __syncthreads();
    if (t < AS) {
        float r = 0.f;
        for (int j = 0; j < AS; j++) r += fabsf(A[t * AS + j]);
        rowsum[t] = r;
    }
    __syncthreads();
    if (t == 0) {
        float n = 0.f;
        for (int i = 0; i < AS; i++) n = fmaxf(n, rowsum[i]);
        nrm_g[mk] = n;
    }
    if (t < AS) { sp_g[mk * AS + t] = sp[t]; isp_g[mk * AS + t] = isp[t]; }
}

// ---------- expm per (m,b,k): Paterson-Stockmeyer deg-9 + squaring ----------
__global__ __launch_bounds__(64) void expm_P(
    const float* __restrict__ Ssym_g, const float* __restrict__ sp_g,
    const float* __restrict__ isp_g, const float* __restrict__ rho_g,
    const float* __restrict__ nrm_g, const float* __restrict__ tauk,
    float* __restrict__ Pout)
{
    const int mbk = blockIdx.x;
    const int ki = mbk % KK;
    const int bi = (mbk / KK) % BB;
    const int mi = mbk / (KK * BB);
    const int mk = mi * KK + ki;
    const int t = threadIdx.x;

    __shared__ float T[ASS], T2[ASS], T3[ASS], Xa[ASS], Xb[ASS];

    const float tau = softplus_f(tauk[mi * BB + bi]) * rho_g[mk];
    const float nt = tau * nrm_g[mk];
    int s = 0;
    if (nt > 1.0f) {
        s = (int)ceilf(log2f(nt));
        if (s < 0) s = 0;
        if (s > 30) s = 30;
    }
    const float sc = ldexpf(tau, -s);

    for (int f = t; f < ASS; f += 64) T[f] = sc * Ssym_g[(size_t)mk * ASS + f];
    __syncthreads();
    mul20(T, T, T2, t);
    mul20(T2, T, T3, t);

    const float C2 = 0.5f, C3 = 1.f/6.f, C4 = 1.f/24.f, C5 = 1.f/120.f,
                C6 = 1.f/720.f, C7 = 1.f/5040.f, C8 = 1.f/40320.f, C9 = 1.f/362880.f;

    for (int f = t; f < ASS; f += 64) {
        int i = f / AS, j = f % AS;
        Xa[f] = ((i == j) ? C6 : 0.f) + C7 * T[f] + C8 * T2[f] + C9 * T3[f];
    }
    __syncthreads();
    mul20(T3, Xa, Xb, t);
    for (int f = t; f < ASS; f += 64) {
        int i = f / AS, j = f % AS;
        Xa[f] = ((i == j) ? C3 : 0.f) + C4 * T[f] + C5 * T2[f] + Xb[f];
    }
    __syncthreads();
    mul20(T3, Xa, Xb, t);
    for (int f = t; f < ASS; f += 64) {
        int i = f / AS, j = f % AS;
        Xa[f] = ((i == j) ? 1.f : 0.f) + T[f] + C2 * T2[f] + Xb[f];
    }
    __syncthreads();
    for (int q = 0; q < s; q++) {
        if ((q & 1) == 0) mul20(Xa, Xa, Xb, t);
        else              mul20(Xb, Xb, Xa, t);
    }

    float* Po = Pout + (size_t)mbk * ASS;
    const float* E = (s & 1) ? Xb : Xa;
    for (int f = t; f < ASS; f += 64) {
        int i = f / AS, j = f % AS;
        Po[f] = isp_g[mk * AS + i] * E[f] * sp_g[mk * AS + j];
    }
}

// ---------- apply: out[mb,l,c] = sum_z seq[mb,l,z] * P[mb,c/20,z,c%20] -----
// 1024 blocks (mb,half) x 320 threads. P staged cooperatively into LDS
// (coalesced), thread j=t%40 owns cols 4j..4j+3 (Preg from LDS). Seq chunks
// (64 rows) double-buffered in LDS; TWO rows in flight per thread for ILP.
// Non-temporal stores for the 335MB write-once out stream.
#define ACC4(A, Sv, Z) \
    A.x = fmaf(Sv, Preg[Z].x, A.x); A.y = fmaf(Sv, Preg[Z].y, A.y); \
    A.z = fmaf(Sv, Preg[Z].z, A.z); A.w = fmaf(Sv, Preg[Z].w, A.w);

__device__ __forceinline__ void nt_store4(float4 v, float* p) {
    nfloat4 nv; nv.x = v.x; nv.y = v.y; nv.z = v.z; nv.w = v.w;
    __builtin_nontemporal_store(nv, (nfloat4*)p);
}

__global__ __launch_bounds__(320, 3) void apply_P(
    const float* __restrict__ seq, const float* __restrict__ Pws,
    float* __restrict__ out)
{
    const int blk = blockIdx.x;
    const int mb = blk >> 1;
    const int half = blk & 1;
    const int t = threadIdx.x;
    const int j = t % 40;        // cols 4j..4j+3
    const int rg = t / 40;       // row group 0..7 (8 rows each per chunk)
    const int ki = j / 5;
    const int s0 = (j % 5) * 4;

    __shared__ __align__(16) float Plds[KK * ASS];   // 12.8 KB
    __shared__ float4 sbuf[2][320];                  // 10.24 KB

    const int rowbase = half * (LL / 2);
    const float* seqb = seq + (size_t)mb * LL * AS;
    float* outb = out + (size_t)mb * LL * (KK * AS);

    // coalesced P stage + overlap first seq chunk load
    {
        const float4* Pg = (const float4*)(Pws + (size_t)mb * KK * ASS);
        for (int idx = t; idx < 800; idx += 320)
            ((float4*)Plds)[idx] = Pg[idx];
    }
    const float4 first = ((const float4*)(seqb + (size_t)rowbase * AS))[t];
    __syncthreads();

    float4 Preg[AS];
    #pragma unroll
    for (int z = 0; z < AS; z++)
        Preg[z] = *(const float4*)&Plds[ki * ASS + z * AS + s0];
    sbuf[0][t] = first;
    __syncthreads();

    for (int c = 0; c < 8; c++) {
        const int cur = c & 1;
        float4 rnext;
        if (c < 7)
            rnext = ((const float4*)(seqb + (size_t)(rowbase + (c + 1) * 64) * AS))[t];
        const int l0 = rowbase + c * 64;
        #pragma unroll
        for (int pr = 0; pr < 4; pr++) {
            const int lrA = rg * 8 + 2 * pr;
            const int lrB = lrA + 1;
            const float4* rowA = &sbuf[cur][lrA * 5];
            const float4* rowB = &sbuf[cur][lrB * 5];
            float4 a0 = {0.f,0.f,0.f,0.f}, a1 = {0.f,0.f,0.f,0.f};
            #pragma unroll
            for (int q = 0; q < 5; q++) {
                float4 svA = rowA[q];
                float4 svB = rowB[q];
                ACC4(a0, svA.x, 4*q+0)  ACC4(a1, svB.x, 4*q+0)
                ACC4(a0, svA.y, 4*q+1)  ACC4(a1, svB.y, 4*q+1)
                ACC4(a0, svA.z, 4*q+2)  ACC4(a1, svB.z, 4*q+2)
                ACC4(a0, svA.w, 4*q+3)  ACC4(a1, svB.w, 4*q+3)
            }
            nt_store4(a0, &outb[(size_t)(l0 + lrA) * 160 + 4 * j]);
            nt_store4(a1, &outb[(size_t)(l0 + lrB) * 160 + 4 * j]);
        }
        if (c < 7) sbuf[cur ^ 1][t] = rnext;
        __syncthreads();
    }
}

extern "C" void kernel_launch(void* const* d_in, const int* in_sizes, int n_in,
                              void* d_out, int out_size, void* d_ws, size_t ws_size,
                              hipStream_t stream) {
    const float* seq  = (const float*)d_in[0];
    const float* exch = (const float*)d_in[1];
    const float* eqk  = (const float*)d_in[2];
    const float* tauk = (const float*)d_in[3];
    const float* pmr  = (const float*)d_in[4];
    float* out = (float*)d_out;

    float* ws   = (float*)d_ws;
    float* Pws  = ws;                        // 4096*400 floats = 6.55 MB
    float* Ssym = ws + (size_t)MM*BB*KK*ASS; // 16*400
    float* spg  = Ssym + MM*KK*ASS;          // 16*20
    float* ispg = spg + MM*KK*AS;            // 16*20
    float* rhog = ispg + MM*KK*AS;           // 16
    float* nrmg = rhog + MM*KK;              // 16

    prep_S<<<dim3(MM * KK), dim3(64), 0, stream>>>(exch, eqk, pmr, Ssym, spg, ispg, rhog, nrmg);
    expm_P<<<dim3(MM * BB * KK), dim3(64), 0, stream>>>(Ssym, spg, ispg, rhog, nrmg, tauk, Pws);
    apply_P<<<dim3(MM * BB * 2), dim3(320), 0, stream>>>(seq, Pws, out);
}

// Round 9
// 113.825 us; speedup vs baseline: 5.2786x; 1.0057x over previous
//
#include <hip/hip_runtime.h>

#define AS 20      // alphabet size
#define ASS 400    // AS*AS
#define KK 8
#define BB 256
#define MM 2
#define LL 1024
#define NPOW 12    // powers S^1..S^12 precomputed per (m,k)

typedef float nfloat4 __attribute__((ext_vector_type(4)));

__device__ __forceinline__ float softplus_f(float x) {
    return x > 20.f ? x : log1pf(expf(x));
}

// ---- 20x20 matmul C = A*B in LDS, 2x4 register-tiled, threads 0..49 ----
__device__ __forceinline__ void mul20(const float* __restrict__ A,
                                      const float* __restrict__ B,
                                      float* __restrict__ C, int t) {
    if (t < 50) {
        const int i2 = (t / 5) * 2;
        const int c4 = (t % 5) * 4;
        float a0[AS], a1[AS];
        #pragma unroll
        for (int q = 0; q < 5; q++) {
            float4 v0 = *(const float4*)&A[i2 * AS + 4 * q];
            float4 v1 = *(const float4*)&A[(i2 + 1) * AS + 4 * q];
            a0[4*q] = v0.x; a0[4*q+1] = v0.y; a0[4*q+2] = v0.z; a0[4*q+3] = v0.w;
            a1[4*q] = v1.x; a1[4*q+1] = v1.y; a1[4*q+2] = v1.z; a1[4*q+3] = v1.w;
        }
        float4 s0 = {0.f,0.f,0.f,0.f}, s1 = {0.f,0.f,0.f,0.f};
        #pragma unroll
        for (int z = 0; z < AS; z++) {
            float4 bv = *(const float4*)&B[z * AS + c4];
            s0.x = fmaf(a0[z], bv.x, s0.x); s0.y = fmaf(a0[z], bv.y, s0.y);
            s0.z = fmaf(a0[z], bv.z, s0.z); s0.w = fmaf(a0[z], bv.w, s0.w);
            s1.x = fmaf(a1[z], bv.x, s1.x); s1.y = fmaf(a1[z], bv.y, s1.y);
            s1.z = fmaf(a1[z], bv.z, s1.z); s1.w = fmaf(a1[z], bv.w, s1.w);
        }
        *(float4*)&C[i2 * AS + c4] = s0;
        *(float4*)&C[(i2 + 1) * AS + c4] = s1;
    }
    __syncthreads();
}

// ------- prep: per (m,k) build Ssym, then powers S^1..S^12 -> global -------
__global__ __launch_bounds__(64) void prep_powers(
    const float* __restrict__ exch, const float* __restrict__ eqk,
    const float* __restrict__ pmr,
    float* __restrict__ Spow_g,   // (mk, NPOW, 400)
    float* __restrict__ sp_g, float* __restrict__ isp_g,
    float* __restrict__ rho_g, float* __restrict__ nrm_g)
{
    const int mk = blockIdx.x;
    const int t = threadIdx.x;
    __shared__ float p[AS], sp[AS], isp[AS], rowsum[AS];
    __shared__ __align__(16) float A[ASS], Pp[ASS], Cc[ASS];
    __shared__ float inv_mue_sh;

    const float* Km = exch + (size_t)mk * ASS;
    const float* ev = eqk + (size_t)mk * AS;

    if (t == 0) {
        float mx = -1e30f;
        for (int i = 0; i < AS; i++) mx = fmaxf(mx, ev[i]);
        float sum = 0.f;
        for (int i = 0; i < AS; i++) { float e = expf(ev[i] - mx); p[i] = e; sum += e; }
        for (int i = 0; i < AS; i++) {
            p[i] /= sum;
            sp[i] = sqrtf(p[i]);
            isp[i] = 1.0f / sp[i];
        }
        rho_g[mk] = softplus_f(pmr[mk]);
    }
    __syncthreads();
    // Pp = R * p_j (reuse as scratch)
    for (int f = t; f < ASS; f += 64) {
        int i = f / AS, j = f % AS;
        float Kv = 0.5f * (Km[i * AS + j] + Km[j * AS + i]);
        float Rv = (i == j) ? 0.f : softplus_f(Kv);
        Pp[f] = Rv * p[j];
    }
    __syncthreads();
    if (t < AS) {
        float r = 0.f;
        for (int j = 0; j < AS; j++) r += Pp[t * AS + j];
        rowsum[t] = r;
    }
    __syncthreads();
    if (t == 0) {
        float mue = 0.f;
        for (int i = 0; i < AS; i++) mue += p[i] * rowsum[i];
        inv_mue_sh = 1.0f / fmaxf(mue, 1e-16f);
    }
    __syncthreads();
    // Cc = raw Ssym
    for (int f = t; f < ASS; f += 64) {
        int i = f / AS, j = f % AS;
        float Qv = (Pp[f] - (i == j ? rowsum[i] : 0.f)) * inv_mue_sh;
        Cc[f] = sp[i] * Qv * isp[j];
    }
    __syncthreads();
    // A = symmetrized Ssym = S^1
    for (int f = t; f < ASS; f += 64) {
        int i = f / AS, j = f % AS;
        A[f] = 0.5f * (Cc[f] + Cc[j * AS + i]);
    }
    __syncthreads();
    if (t < AS) {
        float r = 0.f;
        for (int j = 0; j < AS; j++) r += fabsf(A[t * AS + j]);
        rowsum[t] = r;
    }
    __syncthreads();
    if (t == 0) {
        float n = 0.f;
        for (int i = 0; i < AS; i++) n = fmaxf(n, rowsum[i]);
        nrm_g[mk] = n;
    }
    if (t < AS) { sp_g[mk * AS + t] = sp[t]; isp_g[mk * AS + t] = isp[t]; }

    float* Sg = Spow_g + (size_t)mk * NPOW * ASS;
    for (int f = t; f < ASS; f += 64) { Sg[f] = A[f]; Pp[f] = A[f]; }
    __syncthreads();
    // chain: S^n = S^{n-1} * S
    for (int n = 2; n <= NPOW; ++n) {
        if (n & 1) {
            mul20(Cc, A, Pp, t);
            for (int f = t; f < ASS; f += 64) Sg[(n - 1) * ASS + f] = Pp[f];
        } else {
            mul20(Pp, A, Cc, t);
            for (int f = t; f < ASS; f += 64) Sg[(n - 1) * ASS + f] = Cc[f];
        }
        __syncthreads();
    }
}

// ------- expm per (m,b,k): E = I + sum c_n S^n (no matmuls), s squarings ---
__global__ __launch_bounds__(64) void expm_P2(
    const float* __restrict__ Spow_g, const float* __restrict__ sp_g,
    const float* __restrict__ isp_g, const float* __restrict__ rho_g,
    const float* __restrict__ nrm_g, const float* __restrict__ tauk,
    float* __restrict__ Pout)
{
    const int mbk = blockIdx.x;
    const int ki = mbk % KK;
    const int bi = (mbk / KK) % BB;
    const int mi = mbk / (KK * BB);
    const int mk = mi * KK + ki;
    const int t = threadIdx.x;

    __shared__ __align__(16) float Xa[ASS], Xb[ASS];

    const float tau = softplus_f(tauk[mi * BB + bi]) * rho_g[mk];
    const float nt = tau * nrm_g[mk];
    int s = 0;
    if (nt > 2.0f) {                    // theta = 2
        s = (int)ceilf(log2f(nt * 0.5f));
        if (s < 0) s = 0;
        if (s > 12) s = 12;
    }
    const float sc = ldexpf(tau, -s);

    // coef[n] = sc^n / n!
    float coef[NPOW + 1];
    {
        float scp = 1.f, fact = 1.f;
        #pragma unroll
        for (int n = 1; n <= NPOW; ++n) {
            scp *= sc; fact *= (float)n;
            coef[n] = scp / fact;
        }
    }

    const float* Sg = Spow_g + (size_t)mk * NPOW * ASS;
    float* Po = Pout + (size_t)mbk * ASS;

    if (s == 0) {
        // pure streaming: no LDS, no barrier
        for (int f = t; f < ASS; f += 64) {
            const int i = f / AS, j = f % AS;
            float e = (i == j) ? 1.f : 0.f;
            #pragma unroll
            for (int n = 1; n <= NPOW; ++n)
                e = fmaf(coef[n], Sg[(n - 1) * ASS + f], e);
            Po[f] = isp_g[mk * AS + i] * e * sp_g[mk * AS + j];
        }
    } else {
        for (int f = t; f < ASS; f += 64) {
            const int i = f / AS, j = f % AS;
            float e = (i == j) ? 1.f : 0.f;
            #pragma unroll
            for (int n = 1; n <= NPOW; ++n)
                e = fmaf(coef[n], Sg[(n - 1) * ASS + f], e);
            Xa[f] = e;
        }
        __syncthreads();
        for (int q = 0; q < s; q++) {
            if ((q & 1) == 0) mul20(Xa, Xa, Xb, t);
            else              mul20(Xb, Xb, Xa, t);
        }
        const float* E = (s & 1) ? Xb : Xa;
        for (int f = t; f < ASS; f += 64) {
            const int i = f / AS, j = f % AS;
            Po[f] = isp_g[mk * AS + i] * E[f] * sp_g[mk * AS + j];
        }
    }
}

// ---------- apply (round-8, proven): P in LDS->regs, dbuf seq, 2-row ILP,
// non-temporal out stores ----------
#define ACC4(A, Sv, Z) \
    A.x = fmaf(Sv, Preg[Z].x, A.x); A.y = fmaf(Sv, Preg[Z].y, A.y); \
    A.z = fmaf(Sv, Preg[Z].z, A.z); A.w = fmaf(Sv, Preg[Z].w, A.w);

__device__ __forceinline__ void nt_store4(float4 v, float* p) {
    nfloat4 nv; nv.x = v.x; nv.y = v.y; nv.z = v.z; nv.w = v.w;
    __builtin_nontemporal_store(nv, (nfloat4*)p);
}

__global__ __launch_bounds__(320, 3) void apply_P(
    const float* __restrict__ seq, const float* __restrict__ Pws,
    float* __restrict__ out)
{
    const int blk = blockIdx.x;
    const int mb = blk >> 1;
    const int half = blk & 1;
    const int t = threadIdx.x;
    const int j = t % 40;        // cols 4j..4j+3
    const int rg = t / 40;       // row group 0..7 (8 rows each per chunk)
    const int ki = j / 5;
    const int s0 = (j % 5) * 4;

    __shared__ __align__(16) float Plds[KK * ASS];   // 12.8 KB
    __shared__ float4 sbuf[2][320];                  // 10.24 KB

    const int rowbase = half * (LL / 2);
    const float* seqb = seq + (size_t)mb * LL * AS;
    float* outb = out + (size_t)mb * LL * (KK * AS);

    {
        const float4* Pg = (const float4*)(Pws + (size_t)mb * KK * ASS);
        for (int idx = t; idx < 800; idx += 320)
            ((float4*)Plds)[idx] = Pg[idx];
    }
    const float4 first = ((const float4*)(seqb + (size_t)rowbase * AS))[t];
    __syncthreads();

    float4 Preg[AS];
    #pragma unroll
    for (int z = 0; z < AS; z++)
        Preg[z] = *(const float4*)&Plds[ki * ASS + z * AS + s0];
    sbuf[0][t] = first;
    __syncthreads();

    for (int c = 0; c < 8; c++) {
        const int cur = c & 1;
        float4 rnext;
        if (c < 7)
            rnext = ((const float4*)(seqb + (size_t)(rowbase + (c + 1) * 64) * AS))[t];
        const int l0 = rowbase + c * 64;
        #pragma unroll
        for (int pr = 0; pr < 4; pr++) {
            const int lrA = rg * 8 + 2 * pr;
            const int lrB = lrA + 1;
            const float4* rowA = &sbuf[cur][lrA * 5];
            const float4* rowB = &sbuf[cur][lrB * 5];
            float4 a0 = {0.f,0.f,0.f,0.f}, a1 = {0.f,0.f,0.f,0.f};
            #pragma unroll
            for (int q = 0; q < 5; q++) {
                float4 svA = rowA[q];
                float4 svB = rowB[q];
                ACC4(a0, svA.x, 4*q+0)  ACC4(a1, svB.x, 4*q+0)
                ACC4(a0, svA.y, 4*q+1)  ACC4(a1, svB.y, 4*q+1)
                ACC4(a0, svA.z, 4*q+2)  ACC4(a1, svB.z, 4*q+2)
                ACC4(a0, svA.w, 4*q+3)  ACC4(a1, svB.w, 4*q+3)
            }
            nt_store4(a0, &outb[(size_t)(l0 + lrA) * 160 + 4 * j]);
            nt_store4(a1, &outb[(size_t)(l0 + lrB) * 160 + 4 * j]);
        }
        if (c < 7) sbuf[cur ^ 1][t] = rnext;
        __syncthreads();
    }
}

extern "C" void kernel_launch(void* const* d_in, const int* in_sizes, int n_in,
                              void* d_out, int out_size, void* d_ws, size_t ws_size,
                              hipStream_t stream) {
    const float* seq  = (const float*)d_in[0];
    const float* exch = (const float*)d_in[1];
    const float* eqk  = (const float*)d_in[2];
    const float* tauk = (const float*)d_in[3];
    const float* pmr  = (const float*)d_in[4];
    float* out = (float*)d_out;

    float* ws   = (float*)d_ws;
    float* Pws  = ws;                           // 4096*400 floats = 6.55 MB
    float* Spow = ws + (size_t)MM*BB*KK*ASS;    // 16*12*400 = 307 KB
    float* spg  = Spow + (size_t)MM*KK*NPOW*ASS;
    float* ispg = spg + MM*KK*AS;
    float* rhog = ispg + MM*KK*AS;
    float* nrmg = rhog + MM*KK;

    prep_powers<<<dim3(MM * KK), dim3(64), 0, stream>>>(
        exch, eqk, pmr, Spow, spg, ispg, rhog, nrmg);
    expm_P2<<<dim3(MM * BB * KK), dim3(64), 0, stream>>>(
        Spow, spg, ispg, rhog, nrmg, tauk, Pws);
    apply_P<<<dim3(MM * BB * 2), dim3(320), 0, stream>>>(seq, Pws, out);
}

// Round 10
// 104.805 us; speedup vs baseline: 5.7329x; 1.0861x over previous
//
#include <hip/hip_runtime.h>

#define AS 20      // alphabet size
#define ASS 400    // AS*AS
#define KK 8
#define BB 256
#define MM 2
#define LL 1024
#define NPOW 12    // powers S^1..S^12 per (m,k)

typedef float nfloat4 __attribute__((ext_vector_type(4)));

__device__ __forceinline__ float softplus_f(float x) {
    return x > 20.f ? x : log1pf(expf(x));
}

// wave-synchronous LDS fence (rule #18: lgkmcnt + sched_barrier)
__device__ __forceinline__ void wsync() {
    __builtin_amdgcn_sched_barrier(0);
    asm volatile("s_waitcnt lgkmcnt(0)" ::: "memory");
    __builtin_amdgcn_sched_barrier(0);
}

// wave-level 20x20 matmul C = A*B in LDS, lanes 0..49, 2x4 tiles (round-4 proven)
__device__ __forceinline__ void mul20w(const float* __restrict__ A,
                                       const float* __restrict__ B,
                                       float* __restrict__ C, int lane) {
    wsync();   // make prior LDS writes (own wave) visible; cross-wave via __syncthreads
    if (lane < 50) {
        const int i2 = (lane / 5) * 2;
        const int c4 = (lane % 5) * 4;
        float a0[AS], a1[AS];
        #pragma unroll
        for (int q = 0; q < 5; q++) {
            float4 v0 = *(const float4*)&A[i2 * AS + 4 * q];
            float4 v1 = *(const float4*)&A[(i2 + 1) * AS + 4 * q];
            a0[4*q] = v0.x; a0[4*q+1] = v0.y; a0[4*q+2] = v0.z; a0[4*q+3] = v0.w;
            a1[4*q] = v1.x; a1[4*q+1] = v1.y; a1[4*q+2] = v1.z; a1[4*q+3] = v1.w;
        }
        float4 s0 = {0.f,0.f,0.f,0.f}, s1 = {0.f,0.f,0.f,0.f};
        #pragma unroll
        for (int z = 0; z < AS; z++) {
            float4 bv = *(const float4*)&B[z * AS + c4];
            s0.x = fmaf(a0[z], bv.x, s0.x); s0.y = fmaf(a0[z], bv.y, s0.y);
            s0.z = fmaf(a0[z], bv.z, s0.z); s0.w = fmaf(a0[z], bv.w, s0.w);
            s1.x = fmaf(a1[z], bv.x, s1.x); s1.y = fmaf(a1[z], bv.y, s1.y);
            s1.z = fmaf(a1[z], bv.z, s1.z); s1.w = fmaf(a1[z], bv.w, s1.w);
        }
        *(float4*)&C[i2 * AS + c4] = s0;
        *(float4*)&C[(i2 + 1) * AS + c4] = s1;
    }
}

// ---- prep: per (m,k) Ssym + powers S^1..S^12 via depth-4 parallel tree ----
__global__ __launch_bounds__(256) void prep_powers_par(
    const float* __restrict__ exch, const float* __restrict__ eqk,
    const float* __restrict__ pmr,
    float* __restrict__ Spow_g,   // (mk, NPOW, 400)
    float* __restrict__ sp_g, float* __restrict__ isp_g,
    float* __restrict__ rho_g, float* __restrict__ nrm_g)
{
    const int mk = blockIdx.x;
    const int t = threadIdx.x;
    const int w = t >> 6, lane = t & 63;
    __shared__ float p[AS], sp[AS], isp[AS], rowsum[AS], rowabs[AS];
    __shared__ __align__(16) float SL[NPOW * ASS];   // 19.2 KB

    const float* Km = exch + (size_t)mk * ASS;
    const float* ev = eqk + (size_t)mk * AS;

    if (t < AS) {   // parallel softmax (each lane redundant 20-loop)
        float mx = -1e30f;
        for (int i = 0; i < AS; i++) mx = fmaxf(mx, ev[i]);
        float sum = 0.f;
        for (int i = 0; i < AS; i++) sum += expf(ev[i] - mx);
        float pl = expf(ev[t] - mx) / sum;
        p[t] = pl;
        float sq = sqrtf(pl);
        sp[t] = sq; isp[t] = 1.0f / sq;
    }
    if (t == 0) rho_g[mk] = softplus_f(pmr[mk]);
    __syncthreads();

    float* RP   = SL + ASS;       // scratch (becomes S2 later)
    float* RawS = SL + 2 * ASS;   // scratch (becomes S3 later)
    for (int f = t; f < ASS; f += 256) {
        int i = f / AS, j = f % AS;
        float Kv = 0.5f * (Km[i*AS+j] + Km[j*AS+i]);
        float Rv = (i == j) ? 0.f : softplus_f(Kv);
        RP[f] = Rv * p[j];
    }
    __syncthreads();
    if (t < AS) {
        float r = 0.f;
        for (int j = 0; j < AS; j++) r += RP[t*AS+j];
        rowsum[t] = r;
    }
    __syncthreads();
    float mue = 0.f;
    for (int i = 0; i < AS; i++) mue += p[i] * rowsum[i];
    const float inv_mue = 1.0f / fmaxf(mue, 1e-16f);
    for (int f = t; f < ASS; f += 256) {
        int i = f / AS, j = f % AS;
        float Qv = (RP[f] - (i == j ? rowsum[i] : 0.f)) * inv_mue;
        RawS[f] = sp[i] * Qv * isp[j];
    }
    __syncthreads();
    for (int f = t; f < ASS; f += 256) {
        int i = f / AS, j = f % AS;
        SL[f] = 0.5f * (RawS[f] + RawS[j*AS+i]);   // S^1
    }
    __syncthreads();
    if (t < AS) {
        float r = 0.f;
        for (int j = 0; j < AS; j++) r += fabsf(SL[t*AS+j]);
        rowabs[t] = r;
    }
    __syncthreads();
    if (t == 0) {
        float n = 0.f;
        for (int i = 0; i < AS; i++) n = fmaxf(n, rowabs[i]);
        nrm_g[mk] = n;
    }
    if (t < AS) { sp_g[mk*AS + t] = sp[t]; isp_g[mk*AS + t] = isp[t]; }

    // depth-4 power tree (scratch RP/RawS fully consumed above)
    if (w == 0) mul20w(SL, SL, SL + ASS, lane);                     // S2
    __syncthreads();
    if (w == 0) mul20w(SL + ASS, SL,       SL + 2*ASS, lane);       // S3
    if (w == 1) mul20w(SL + ASS, SL + ASS, SL + 3*ASS, lane);       // S4
    __syncthreads();
    if (w == 0) mul20w(SL + 3*ASS, SL,         SL + 4*ASS, lane);   // S5
    if (w == 1) mul20w(SL + 3*ASS, SL + ASS,   SL + 5*ASS, lane);   // S6
    if (w == 2) mul20w(SL + 3*ASS, SL + 2*ASS, SL + 6*ASS, lane);   // S7
    if (w == 3) mul20w(SL + 3*ASS, SL + 3*ASS, SL + 7*ASS, lane);   // S8
    __syncthreads();
    if (w == 0) mul20w(SL + 7*ASS, SL,         SL + 8*ASS, lane);   // S9
    if (w == 1) mul20w(SL + 7*ASS, SL + ASS,   SL + 9*ASS, lane);   // S10
    if (w == 2) mul20w(SL + 7*ASS, SL + 2*ASS, SL + 10*ASS, lane);  // S11
    if (w == 3) mul20w(SL + 7*ASS, SL + 3*ASS, SL + 11*ASS, lane);  // S12
    __syncthreads();

    float* Sg = Spow_g + (size_t)mk * NPOW * ASS;
    for (int f = t; f < NPOW * ASS; f += 256) Sg[f] = SL[f];
}

// ---- fused: per (m,b,half) block — prologue builds 8 P's from power sums
// (+ rare squarings), then round-8 apply loop ----
#define ACC4(A, Sv, Z) \
    A.x = fmaf(Sv, Preg[Z].x, A.x); A.y = fmaf(Sv, Preg[Z].y, A.y); \
    A.z = fmaf(Sv, Preg[Z].z, A.z); A.w = fmaf(Sv, Preg[Z].w, A.w);

__device__ __forceinline__ void nt_store4(float4 v, float* p) {
    nfloat4 nv; nv.x = v.x; nv.y = v.y; nv.z = v.z; nv.w = v.w;
    __builtin_nontemporal_store(nv, (nfloat4*)p);
}

__global__ __launch_bounds__(320, 3) void fused_apply(
    const float* __restrict__ seq, const float* __restrict__ Spow_g,
    const float* __restrict__ sp_g, const float* __restrict__ isp_g,
    const float* __restrict__ rho_g, const float* __restrict__ nrm_g,
    const float* __restrict__ tauk, float* __restrict__ out)
{
    const int blk = blockIdx.x;
    const int mb = blk >> 1;
    const int half = blk & 1;
    const int mi = mb / BB;
    const int t = threadIdx.x;
    const int w = t >> 6;
    const int lane = t & 63;

    __shared__ __align__(16) float Plds[KK * ASS];   // 12.8 KB
    __shared__ __align__(16) float4 sbuf[2][320];    // 10.24 KB
    __shared__ __align__(16) float Tmp[5][ASS];      // 8 KB wave squaring scratch
    __shared__ float coefs[KK][NPOW];
    __shared__ float spk[KK * AS], ispk[KK * AS];
    __shared__ float scs[KK];
    __shared__ int ssh[KK];

    const int rowbase = half * (LL / 2);
    const float* seqb = seq + (size_t)mb * LL * AS;
    float* outb = out + (size_t)mb * LL * (KK * AS);

    // issue first seq chunk load immediately — overlaps whole prologue
    const float4 first = ((const float4*)(seqb + (size_t)rowbase * AS))[t];

    if (t < KK) {
        const float tau = softplus_f(tauk[mb]) * rho_g[mi * KK + t];
        const float nt = tau * nrm_g[mi * KK + t];
        int s = 0;
        if (nt > 2.0f) {                 // theta = 2 (round-9 proven)
            s = (int)ceilf(log2f(nt * 0.5f));
            if (s < 0) s = 0;
            if (s > 12) s = 12;
        }
        ssh[t] = s;
        scs[t] = ldexpf(tau, -s);
    }
    if (t < KK * AS) {   // 160 threads
        spk[t]  = sp_g [mi * KK * AS + t];
        ispk[t] = isp_g[mi * KK * AS + t];
    }
    __syncthreads();
    if (t < KK * NPOW) {  // 96 threads: coefs[k][n-1] = sc^n / n!
        const int k = t / NPOW, n = t % NPOW + 1;
        const float sc = scs[k];
        float scp = sc, fact = 1.f;
        for (int q = 2; q <= n; ++q) { scp *= sc; fact *= (float)q; }
        coefs[k][n - 1] = scp / fact;
    }
    __syncthreads();

    // Taylor sums: Plds[k][f] = I + sum_n coef[k][n] * S^n[f]
    {
        const float* Sbase = Spow_g + (size_t)mi * KK * NPOW * ASS;
        #pragma unroll 2
        for (int e = t; e < KK * ASS; e += 320) {
            const int k = e / ASS;
            const int f = e - k * ASS;
            const int i = f / AS, jj = f - i * AS;
            const float* Sg = Sbase + (size_t)k * NPOW * ASS + f;
            float acc = (i == jj) ? 1.f : 0.f;
            #pragma unroll
            for (int n = 1; n <= NPOW; ++n)
                acc = fmaf(coefs[k][n - 1], Sg[(n - 1) * ASS], acc);
            Plds[e] = acc;
        }
    }
    __syncthreads();

    // squarings (wave w owns k=w, and k=w+5 for w<3); s is wave-uniform
    {
        const int nk = (w < 3) ? 2 : 1;
        for (int pi = 0; pi < nk; ++pi) {
            const int k = (pi == 0) ? w : w + 5;
            const int s = ssh[k];
            float* Pk = &Plds[k * ASS];
            float* Tw = &Tmp[w][0];
            for (int q = 0; q < s; ++q) {
                if ((q & 1) == 0) mul20w(Pk, Pk, Tw, lane);
                else              mul20w(Tw, Tw, Pk, lane);
            }
            if (s & 1) {   // result landed in Tw -> copy back
                wsync();
                if (lane < 50) {
                    #pragma unroll
                    for (int u = 0; u < 8; ++u) Pk[lane * 8 + u] = Tw[lane * 8 + u];
                }
            }
        }
    }
    __syncthreads();

    // diag scale: P = diag(isp) * E * diag(sp)
    for (int e = t; e < KK * ASS; e += 320) {
        const int k = e / ASS;
        const int f = e - k * ASS;
        const int i = f / AS, jj = f - i * AS;
        Plds[e] *= ispk[k * AS + i] * spk[k * AS + jj];
    }
    __syncthreads();

    // ---- round-8 apply loop (proven) ----
    const int j = t % 40;
    const int rg = t / 40;
    const int ki = j / 5;
    const int s0 = (j % 5) * 4;

    float4 Preg[AS];
    #pragma unroll
    for (int z = 0; z < AS; z++)
        Preg[z] = *(const float4*)&Plds[ki * ASS + z * AS + s0];
    sbuf[0][t] = first;
    __syncthreads();

    for (int c = 0; c < 8; c++) {
        const int cur = c & 1;
        float4 rnext;
        if (c < 7)
            rnext = ((const float4*)(seqb + (size_t)(rowbase + (c + 1) * 64) * AS))[t];
        const int l0 = rowbase + c * 64;
        #pragma unroll
        for (int pr = 0; pr < 4; pr++) {
            const int lrA = rg * 8 + 2 * pr;
            const int lrB = lrA + 1;
            const float4* rowA = &sbuf[cur][lrA * 5];
            const float4* rowB = &sbuf[cur][lrB * 5];
            float4 a0 = {0.f,0.f,0.f,0.f}, a1 = {0.f,0.f,0.f,0.f};
            #pragma unroll
            for (int q = 0; q < 5; q++) {
                float4 svA = rowA[q];
                float4 svB = rowB[q];
                ACC4(a0, svA.x, 4*q+0)  ACC4(a1, svB.x, 4*q+0)
                ACC4(a0, svA.y, 4*q+1)  ACC4(a1, svB.y, 4*q+1)
                ACC4(a0, svA.z, 4*q+2)  ACC4(a1, svB.z, 4*q+2)
                ACC4(a0, svA.w, 4*q+3)  ACC4(a1, svB.w, 4*q+3)
            }
            nt_store4(a0, &outb[(size_t)(l0 + lrA) * 160 + 4 * j]);
            nt_store4(a1, &outb[(size_t)(l0 + lrB) * 160 + 4 * j]);
        }
        if (c < 7) sbuf[cur ^ 1][t] = rnext;
        __syncthreads();
    }
}

extern "C" void kernel_launch(void* const* d_in, const int* in_sizes, int n_in,
                              void* d_out, int out_size, void* d_ws, size_t ws_size,
                              hipStream_t stream) {
    const float* seq  = (const float*)d_in[0];
    const float* exch = (const float*)d_in[1];
    const float* eqk  = (const float*)d_in[2];
    const float* tauk = (const float*)d_in[3];
    const float* pmr  = (const float*)d_in[4];
    float* out = (float*)d_out;

    float* ws   = (float*)d_ws;
    float* Spow = ws;                                  // 16*12*400 = 307 KB
    float* spg  = Spow + (size_t)MM * KK * NPOW * ASS;
    float* ispg = spg + MM * KK * AS;
    float* rhog = ispg + MM * KK * AS;
    float* nrmg = rhog + MM * KK;

    prep_powers_par<<<dim3(MM * KK), dim3(256), 0, stream>>>(
        exch, eqk, pmr, Spow, spg, ispg, rhog, nrmg);
    fused_apply<<<dim3(MM * BB * 2), dim3(320), 0, stream>>>(
        seq, Spow, spg, ispg, rhog, nrmg, tauk, out);
}